// Round 9
// baseline (633.312 us; speedup 1.0000x reference)
//
#include <hip/hip_runtime.h>

// PointPillarScatter, OUTPUT-LINEAR gather (fill-mimicking write stream):
//   pass 1: winner[b*SS+s] = max p writing (b,s)  (last-write-wins, verified R1)
//   pass 2: out is written in natural linear order; each wave owns a contiguous
//           ~105KB run of 1KB chunks (4096 streams, like the 6.3TB/s fill).
//           Per chunk: coalesced winner int4 + 4 clamped pf reads + float4 store.
//           No LDS, no barriers; manual 3-stage pipeline (W -> PF -> ST, width 2).

#define NXx 432
#define NYy 496
#define SS  (NXx * NYy)       // 214272
#define CC  64
#define CPP (SS / 256)        // 837 chunks (1KB) per plane

typedef float f4 __attribute__((ext_vector_type(4)));

__global__ void winner_kernel(const int* __restrict__ cb,
                              const int* __restrict__ cz,
                              const int* __restrict__ cy,
                              const int* __restrict__ cx,
                              int* __restrict__ winner, int P) {
    int p = blockIdx.x * blockDim.x + threadIdx.x;
    if (p < P) {
        int slot = cb[p] * SS + cz[p] + cy[p] * NXx + cx[p];
        atomicMax(&winner[slot], p);
    }
}

__global__ __launch_bounds__(256)
void gather_kernel(const float* __restrict__ pf,
                   const int* __restrict__ winner,
                   float* __restrict__ out,
                   int nchunks, int nwaves) {
    const int wid  = (blockIdx.x * 256 + threadIdx.x) >> 6;
    const int lane = threadIdx.x & 63;

    // contiguous run assignment: first `rem` waves get base+1 chunks
    const int base  = nchunks / nwaves;
    const int rem   = nchunks - base * nwaves;
    const int start = wid * base + (wid < rem ? wid : rem);
    const int count = base + (wid < rem ? 1 : 0);
    const int end   = start + count;
    const int last  = end - 1;

    auto clampg = [&](int g) { return g < last ? g : last; };

    auto ldw = [&](int g) -> int4 {           // coalesced 1KB winner read
        int plane = g / CPP;                   // magic-mul const divide
        int off   = g - plane * CPP;
        int b     = plane >> 6;
        return *reinterpret_cast<const int4*>(
            winner + (size_t)b * SS + off * 256 + 4 * lane);
    };
    auto ldp = [&](int g, int4 w) -> f4 {      // 4 clamped pf gathers
        int plane = g / CPP;
        int c     = plane & 63;
        f4 v;
        v.x = pf[((size_t)max(w.x, 0) << 6) + c];
        v.y = pf[((size_t)max(w.y, 0) << 6) + c];
        v.z = pf[((size_t)max(w.z, 0) << 6) + c];
        v.w = pf[((size_t)max(w.w, 0) << 6) + c];
        v.x = (w.x >= 0) ? v.x : 0.0f;
        v.y = (w.y >= 0) ? v.y : 0.0f;
        v.z = (w.z >= 0) ? v.z : 0.0f;
        v.w = (w.w >= 0) ? v.w : 0.0f;
        return v;
    };

    // 3-stage pipeline prologue: winner 4 ahead, pf 2 ahead
    int4 w2 = ldw(clampg(start + 2));
    int4 w3 = ldw(clampg(start + 3));
    f4 p0, p1;
    {
        int4 w0 = ldw(clampg(start));
        int4 w1 = ldw(clampg(start + 1));
        p0 = ldp(clampg(start), w0);
        p1 = ldp(clampg(start + 1), w1);
    }

    for (int g = start; g < end; g += 2) {
        int4 nw2 = ldw(clampg(g + 4));         // issue earliest-need-last first
        int4 nw3 = ldw(clampg(g + 5));
        *reinterpret_cast<f4*>(out + (size_t)g * 256 + 4 * lane) = p0;
        if (g + 1 < end)
            *reinterpret_cast<f4*>(out + (size_t)(g + 1) * 256 + 4 * lane) = p1;
        p0 = ldp(clampg(g + 2), w2);           // issue pf for next iteration
        p1 = ldp(clampg(g + 3), w3);
        w2 = nw2; w3 = nw3;
    }
}

extern "C" void kernel_launch(void* const* d_in, const int* in_sizes, int n_in,
                              void* d_out, int out_size, void* d_ws, size_t ws_size,
                              hipStream_t stream) {
    const float* pf = (const float*)d_in[0];
    const int* cb   = (const int*)d_in[1];
    const int* cz   = (const int*)d_in[2];
    const int* cy   = (const int*)d_in[3];
    const int* cx   = (const int*)d_in[4];
    float* out      = (float*)d_out;

    const int P      = in_sizes[1];           // number of pillars
    const int nslots = out_size / CC;         // B * SS = 1,714,176

    int* winner = (int*)d_ws;                 // nslots ints = 6.86 MB
    hipMemsetAsync(winner, 0xFF, (size_t)nslots * sizeof(int), stream);  // -1

    winner_kernel<<<(P + 255) / 256, 256, 0, stream>>>(cb, cz, cy, cx, winner, P);

    const int nchunks = out_size / 256;       // 428,544 1KB chunks
    int nwaves = 4096;                        // 1024 blocks -> 4 blocks/CU
    if (nwaves > nchunks) nwaves = nchunks;
    gather_kernel<<<nwaves / 4, 256, 0, stream>>>(pf, winner, out, nchunks, nwaves);
}

// Round 11
// 502.250 us; speedup vs baseline: 1.2610x; 1.2610x over previous
//
#include <hip/hip_runtime.h>

// PointPillarScatter, DENSE-SWEEP gather (fill-structured write window):
//   pass 1: winner[b*SS+s] = max p writing (b,s)  (last-write-wins, verified R1)
//   pass 2: grid-stride over chunk-groups (b, c4, s256). Consecutive groups =
//           consecutive s-chunks, so the whole grid writes ~20 dense planes
//           sweeping linearly (fill-like DRAM row locality). winner 1KB and
//           each 64B pf line are re-used across c4 phases within the sweep
//           window -> L2-hit; compulsory HBM reads ~40MB. In-register 4x4
//           transpose, branchless zeros, no LDS, no barriers.

#define NXx 432
#define NYy 496
#define SS  (NXx * NYy)   // 214272
#define CC  64
#define CPP (SS / 256)    // 837 1KB-chunks per plane

typedef float f4 __attribute__((ext_vector_type(4)));

__global__ void winner_kernel(const int* __restrict__ cb,
                              const int* __restrict__ cz,
                              const int* __restrict__ cy,
                              const int* __restrict__ cx,
                              int* __restrict__ winner, int P) {
    int p = blockIdx.x * blockDim.x + threadIdx.x;
    if (p < P) {
        int slot = cb[p] * SS + cz[p] + cy[p] * NXx + cx[p];
        atomicMax(&winner[slot], p);
    }
}

__global__ __launch_bounds__(256)
void scatter_kernel(const float* __restrict__ pf,
                    const int* __restrict__ winner,
                    float* __restrict__ out, int ngroups) {
    const int nwaves = (gridDim.x * 256) >> 6;
    const int wid    = (blockIdx.x * 256 + threadIdx.x) >> 6;
    const int lane   = threadIdx.x & 63;

    for (int g = wid; g < ngroups; g += nwaves) {
        const int p4 = g / CPP;            // b*16 + c4   (magic-mul)
        const int sc = g - p4 * CPP;       // s-chunk within plane
        const int b  = p4 >> 4;
        const int c4 = p4 & 15;

        // coalesced 1KB winner read (L2-hit after first c4 phase)
        const int4 w = *reinterpret_cast<const int4*>(
            winner + (size_t)b * SS + sc * 256 + 4 * lane);

        // one 16B read per winner row (64B line shared across 4 c4 phases)
        f4 r0 = *reinterpret_cast<const f4*>(pf + ((size_t)max(w.x, 0) << 6) + c4 * 4);
        f4 r1 = *reinterpret_cast<const f4*>(pf + ((size_t)max(w.y, 0) << 6) + c4 * 4);
        f4 r2 = *reinterpret_cast<const f4*>(pf + ((size_t)max(w.z, 0) << 6) + c4 * 4);
        f4 r3 = *reinterpret_cast<const f4*>(pf + ((size_t)max(w.w, 0) << 6) + c4 * 4);
        const float s0 = (w.x >= 0) ? 1.0f : 0.0f;
        const float s1 = (w.y >= 0) ? 1.0f : 0.0f;
        const float s2 = (w.z >= 0) ? 1.0f : 0.0f;
        const float s3 = (w.w >= 0) ? 1.0f : 0.0f;
        r0 *= s0; r1 *= s1; r2 *= s2; r3 *= s3;

        // 4 dense 1KB stores to channels c4*4..+3 (4 sweeping windows)
        float* ob = out + ((size_t)(b * CC + c4 * 4)) * SS + sc * 256 + 4 * lane;
        f4 o;
        o.x = r0.x; o.y = r1.x; o.z = r2.x; o.w = r3.x;
        *reinterpret_cast<f4*>(ob) = o;
        o.x = r0.y; o.y = r1.y; o.z = r2.y; o.w = r3.y;
        *reinterpret_cast<f4*>(ob + SS) = o;
        o.x = r0.z; o.y = r1.z; o.z = r2.z; o.w = r3.z;
        *reinterpret_cast<f4*>(ob + 2 * (size_t)SS) = o;
        o.x = r0.w; o.y = r1.w; o.z = r2.w; o.w = r3.w;
        *reinterpret_cast<f4*>(ob + 3 * (size_t)SS) = o;
    }
}

extern "C" void kernel_launch(void* const* d_in, const int* in_sizes, int n_in,
                              void* d_out, int out_size, void* d_ws, size_t ws_size,
                              hipStream_t stream) {
    const float* pf = (const float*)d_in[0];
    const int* cb   = (const int*)d_in[1];
    const int* cz   = (const int*)d_in[2];
    const int* cy   = (const int*)d_in[3];
    const int* cx   = (const int*)d_in[4];
    float* out      = (float*)d_out;

    const int P      = in_sizes[1];           // number of pillars
    const int nslots = out_size / CC;         // B * SS = 1,714,176

    int* winner = (int*)d_ws;                 // nslots ints = 6.86 MB
    hipMemsetAsync(winner, 0xFF, (size_t)nslots * sizeof(int), stream);  // -1

    winner_kernel<<<(P + 255) / 256, 256, 0, stream>>>(cb, cz, cy, cx, winner, P);

    const int ngroups = out_size / 1024;      // 107,136 chunk-groups
    scatter_kernel<<<1024, 256, 0, stream>>>(pf, winner, out, ngroups);
}